// Round 1
// baseline (727.992 us; speedup 1.0000x reference)
//
#include <hip/hip_runtime.h>
#include <hip/hip_bf16.h>

#define NEG_SLOPE 0.2f

typedef __bf16 v8bf __attribute__((ext_vector_type(8)));
typedef float  v4f  __attribute__((ext_vector_type(4)));

__device__ __forceinline__ unsigned short f2b(float f) {
    unsigned u = __builtin_bit_cast(unsigned, f);
    u += 0x7FFFu + ((u >> 16) & 1u);           // RNE to bf16
    return (unsigned short)(u >> 16);
}
__device__ __forceinline__ float b2f(unsigned short h) {
    unsigned u = ((unsigned)h) << 16;
    return __builtin_bit_cast(float, u);
}
__device__ __forceinline__ void atomAddF(float* p, float v) {
    __hip_atomic_fetch_add(p, v, __ATOMIC_RELAXED, __HIP_MEMORY_SCOPE_AGENT);
}

// ---------------------------------------------------------------------------
// K0: pack [Wl|Wr|Ws] -> Wt bf16, transposed to [n(384)][k(128)] so MFMA
// B-fragments are contiguous 16B loads (lane n=lane&15 holds k=quad*8+j).
// ---------------------------------------------------------------------------
__global__ __launch_bounds__(256) void k0_wprep(
    const float* __restrict__ Wl, const float* __restrict__ Wr,
    const float* __restrict__ Ws, unsigned short* __restrict__ Wt)
{
    int t = blockIdx.x * 256 + threadIdx.x;
    if (t >= 384 * 128) return;
    int nn = t >> 7, k = t & 127;
    const float* W = (nn < 128) ? Wl : ((nn < 256) ? Wr : Ws);
    Wt[t] = f2b(W[k * 128 + (nn & 127)]);
}

// ---------------------------------------------------------------------------
// K1: per wave, 16 nodes x 384 cols via mfma_f32_16x16x32_bf16 (24 n-tiles,
// 4 k-steps). Epilogue: write xl/xr/sk (bf16), and initialize agg/denom with
// the self-loop softmax term (non-atomic; agg = exp(e_self)*xl, denom = exp).
// sk absorbs both biases: sk = raw@Ws + bs + bias_gat.
// A layout: m=lane&15, k=quad*8+j.  C/D: col=lane&15, row=quad*4+reg.
// ---------------------------------------------------------------------------
__global__ __launch_bounds__(256) void k1_gemm(
    const float* __restrict__ x, const float* __restrict__ tf,
    const unsigned short* __restrict__ Wt,
    const float* __restrict__ att, const float* __restrict__ bias_gat,
    const float* __restrict__ bs,
    unsigned short* __restrict__ xl_b, unsigned short* __restrict__ xr_b,
    unsigned short* __restrict__ sk_b,
    float* __restrict__ agg, float* __restrict__ denom, int N)
{
    const int lane = threadIdx.x & 63;
    const int wave = blockIdx.x * (blockDim.x >> 6) + (threadIdx.x >> 6);
    const int base = wave * 16;
    if (base >= N) return;
    const int nidx = lane & 15;
    const int quad = lane >> 4;

    int anode = base + nidx; if (anode >= N) anode = N - 1;
    const float* xrow = x  + (size_t)anode * 126;
    const float* trow = tf + (size_t)anode * 2;

    v4f acc[24];
    #pragma unroll
    for (int i = 0; i < 24; ++i) acc[i] = 0.0f;

    #pragma unroll
    for (int ks = 0; ks < 4; ++ks) {
        union { v8bf v; unsigned short u[8]; } aF;
        const int k0 = ks * 32 + quad * 8;
        #pragma unroll
        for (int j = 0; j < 8; ++j) {
            const int k = k0 + j;
            float v = (k < 126) ? xrow[k] : trow[k - 126];
            aF.u[j] = f2b(v);
        }
        const unsigned short* wbase = Wt + (size_t)nidx * 128 + (size_t)k0;
        #pragma unroll
        for (int nt = 0; nt < 24; ++nt) {
            v8bf bF = *reinterpret_cast<const v8bf*>(wbase + nt * (16 * 128));
            acc[nt] = __builtin_amdgcn_mfma_f32_16x16x32_bf16(aF.v, bF, acc[nt], 0, 0, 0);
        }
    }

    float attv[8], biasv[8];
    #pragma unroll
    for (int h = 0; h < 8; ++h) {
        attv[h]  = att[h * 16 + nidx];
        biasv[h] = bs[h * 16 + nidx] + bias_gat[h * 16 + nidx];
    }

    // store xl / xr / sk (bf16)
    #pragma unroll
    for (int reg = 0; reg < 4; ++reg) {
        const int node = base + quad * 4 + reg;
        if (node < N) {
            const size_t rb = (size_t)node * 128;
            #pragma unroll
            for (int nt = 0; nt < 8; ++nt) {
                const int col = nt * 16 + nidx;
                xl_b[rb + col] = f2b(acc[nt][reg]);
                xr_b[rb + col] = f2b(acc[nt + 8][reg]);
                sk_b[rb + col] = f2b(acc[nt + 16][reg] + biasv[nt]);
            }
        }
    }

    // self-loop: e = att . lrelu(xl+xr); agg = exp(e)*xl; denom = exp(e)
    #pragma unroll
    for (int h = 0; h < 8; ++h) {
        v4f t;
        #pragma unroll
        for (int reg = 0; reg < 4; ++reg) {
            float mv = acc[h][reg] + acc[h + 8][reg];
            float l  = mv > 0.0f ? mv : NEG_SLOPE * mv;
            t[reg] = l * attv[h];
        }
        #pragma unroll
        for (int off = 8; off >= 1; off >>= 1) {
            #pragma unroll
            for (int reg = 0; reg < 4; ++reg)
                t[reg] += __shfl_xor(t[reg], off, 64);   // 16-lane group all-reduce
        }
        #pragma unroll
        for (int reg = 0; reg < 4; ++reg) {
            const int node = base + quad * 4 + reg;
            if (node < N) {
                float ee = expf(t[reg]);
                agg[(size_t)node * 128 + h * 16 + nidx] = ee * acc[h][reg];
                if (nidx == 0) denom[(size_t)node * 8 + h] = ee;
            }
        }
    }
}

// ---------------------------------------------------------------------------
// K3: one wave per edge. Lane covers elements p=lane and p=lane+64
// (p = h*16+c). Per-head 16-lane butterfly all-reduce -> e_h; unnormalized
// scatter: agg[dst] += exp(e)*xl[src], denom[dst][h] += exp(e).
// ---------------------------------------------------------------------------
__global__ __launch_bounds__(256) void k3_edge(
    const int* __restrict__ ei, int E,
    const unsigned short* __restrict__ xl_b,
    const unsigned short* __restrict__ xr_b,
    const float* __restrict__ att,
    float* __restrict__ agg, float* __restrict__ denom)
{
    const int w = (int)((blockIdx.x * (size_t)blockDim.x + threadIdx.x) >> 6);
    const int lane = threadIdx.x & 63;
    if (w >= E) return;
    const int src = ei[w];
    const int dst = ei[E + w];
    const size_t sb = (size_t)src * 128, db = (size_t)dst * 128;

    float xl0 = b2f(xl_b[sb + lane]);
    float xl1 = b2f(xl_b[sb + 64 + lane]);
    float m0 = xl0 + b2f(xr_b[db + lane]);
    float m1 = xl1 + b2f(xr_b[db + 64 + lane]);
    float l0 = m0 > 0.0f ? m0 : NEG_SLOPE * m0;
    float l1 = m1 > 0.0f ? m1 : NEG_SLOPE * m1;
    float t0 = l0 * att[lane];
    float t1 = l1 * att[64 + lane];
    #pragma unroll
    for (int off = 8; off >= 1; off >>= 1) {
        t0 += __shfl_xor(t0, off, 64);
        t1 += __shfl_xor(t1, off, 64);
    }
    float e0 = expf(t0), e1 = expf(t1);
    atomAddF(&agg[db + lane],      e0 * xl0);
    atomAddF(&agg[db + 64 + lane], e1 * xl1);
    if ((lane & 15) == 0) {
        atomAddF(&denom[(size_t)dst * 8 + (lane >> 4)],     e0);
        atomAddF(&denom[(size_t)dst * 8 + 4 + (lane >> 4)], e1);
    }
}

// ---------------------------------------------------------------------------
// K4: one wave per node: g = agg/denom + sk; elu; dot(Wo); sigmoid.
// ---------------------------------------------------------------------------
__global__ __launch_bounds__(256) void k4_final(
    const float* __restrict__ agg, const float* __restrict__ denom,
    const unsigned short* __restrict__ sk_b,
    const float* __restrict__ Wo, const float* __restrict__ bo,
    float* __restrict__ out, int N)
{
    const int w = (int)((blockIdx.x * (size_t)blockDim.x + threadIdx.x) >> 6);
    const int lane = threadIdx.x & 63;
    if (w >= N) return;
    const size_t b = (size_t)w * 128;
    float d0 = denom[(size_t)w * 8 + (lane >> 4)]     + 1e-16f;
    float d1 = denom[(size_t)w * 8 + 4 + (lane >> 4)] + 1e-16f;
    float g0 = agg[b + lane]      / d0 + b2f(sk_b[b + lane]);
    float g1 = agg[b + 64 + lane] / d1 + b2f(sk_b[b + 64 + lane]);
    float c0 = g0 > 0.0f ? g0 : expf(g0) - 1.0f;
    float c1 = g1 > 0.0f ? g1 : expf(g1) - 1.0f;
    float s = c0 * Wo[lane] + c1 * Wo[64 + lane];
    #pragma unroll
    for (int off = 32; off >= 1; off >>= 1) s += __shfl_xor(s, off, 64);
    if (lane == 0) out[w] = 1.0f / (1.0f + expf(-(s + bo[0])));
}

// ---------------------------------------------------------------------------
extern "C" void kernel_launch(void* const* d_in, const int* in_sizes, int n_in,
                              void* d_out, int out_size, void* d_ws, size_t ws_size,
                              hipStream_t stream) {
    const float* x   = (const float*)d_in[0];
    const float* tf  = (const float*)d_in[1];
    const int*   ei  = (const int*)  d_in[2];
    const float* Wl  = (const float*)d_in[3];
    const float* Wr  = (const float*)d_in[4];
    const float* att = (const float*)d_in[5];
    const float* bg  = (const float*)d_in[6];
    const float* Ws  = (const float*)d_in[7];
    const float* bs  = (const float*)d_in[8];
    const float* Wo  = (const float*)d_in[9];
    const float* bo  = (const float*)d_in[10];
    float* out = (float*)d_out;

    const int N = in_sizes[0] / 126;
    const int E = in_sizes[2] / 2;

    char* ws = (char*)d_ws;
    unsigned short* Wt   = (unsigned short*)ws; ws += (size_t)384 * 128 * 2;
    unsigned short* xl_b = (unsigned short*)ws; ws += (size_t)N * 128 * 2;
    unsigned short* xr_b = (unsigned short*)ws; ws += (size_t)N * 128 * 2;
    unsigned short* sk_b = (unsigned short*)ws; ws += (size_t)N * 128 * 2;
    float* agg   = (float*)ws;                  ws += (size_t)N * 128 * 4;
    float* denom = (float*)ws;                  ws += (size_t)N * 8 * 4;
    // total ws use ~131.3 MB

    hipLaunchKernelGGL(k0_wprep, dim3(192), dim3(256), 0, stream, Wl, Wr, Ws, Wt);

    const int waves1 = (N + 15) / 16;
    hipLaunchKernelGGL(k1_gemm, dim3((waves1 + 3) / 4), dim3(256), 0, stream,
                       x, tf, Wt, att, bg, bs, xl_b, xr_b, sk_b, agg, denom, N);

    hipLaunchKernelGGL(k3_edge, dim3((E + 3) / 4), dim3(256), 0, stream,
                       ei, E, xl_b, xr_b, att, agg, denom);

    hipLaunchKernelGGL(k4_final, dim3((N + 3) / 4), dim3(256), 0, stream,
                       agg, denom, sk_b, Wo, bo, out, N);
}

// Round 2
// 394.734 us; speedup vs baseline: 1.8443x; 1.8443x over previous
//
#include <hip/hip_runtime.h>
#include <hip/hip_bf16.h>

#define NEG_SLOPE 0.2f

typedef __bf16 v8bf __attribute__((ext_vector_type(8)));
typedef float  v4f  __attribute__((ext_vector_type(4)));

__device__ __forceinline__ unsigned short f2b(float f) {
    unsigned u = __builtin_bit_cast(unsigned, f);
    u += 0x7FFFu + ((u >> 16) & 1u);           // RNE to bf16
    return (unsigned short)(u >> 16);
}
__device__ __forceinline__ float b2f(unsigned short h) {
    unsigned u = ((unsigned)h) << 16;
    return __builtin_bit_cast(float, u);
}
__device__ __forceinline__ void b2f2(unsigned u, float& lo, float& hi) {
    lo = __builtin_bit_cast(float, u << 16);
    hi = __builtin_bit_cast(float, u & 0xFFFF0000u);
}
__device__ __forceinline__ int atomIncI(int* p) {
    return __hip_atomic_fetch_add(p, 1, __ATOMIC_RELAXED, __HIP_MEMORY_SCOPE_AGENT);
}

// ---------------------------------------------------------------------------
// K0: pack [Wl|Wr|Ws] -> Wt bf16, transposed to [n(384)][k(128)] so MFMA
// B-fragments are contiguous 16B loads.
// ---------------------------------------------------------------------------
__global__ __launch_bounds__(256) void k0_wprep(
    const float* __restrict__ Wl, const float* __restrict__ Wr,
    const float* __restrict__ Ws, unsigned short* __restrict__ Wt)
{
    int t = blockIdx.x * 256 + threadIdx.x;
    if (t >= 384 * 128) return;
    int nn = t >> 7, k = t & 127;
    const float* W = (nn < 128) ? Wl : ((nn < 256) ? Wr : Ws);
    Wt[t] = f2b(W[k * 128 + (nn & 127)]);
}

// ---------------------------------------------------------------------------
// KZ: zero the CSR int region (counts | offsets | cursor = 3N ints).
// (ws is poisoned 0xAA before every call; we must init ourselves.)
// ---------------------------------------------------------------------------
__global__ __launch_bounds__(256) void kz_zero(int* __restrict__ p, int n)
{
    int t = blockIdx.x * 256 + threadIdx.x;
    if (t < n) p[t] = 0;
}

// ---------------------------------------------------------------------------
// KH: histogram of in-degree. counts[dst]++ per edge.
// ---------------------------------------------------------------------------
__global__ __launch_bounds__(256) void kh_hist(
    const int* __restrict__ ei, int E, int* __restrict__ counts)
{
    int t = blockIdx.x * 256 + threadIdx.x;
    if (t < E) atomIncI(&counts[ei[E + t]]);
}

// ---------------------------------------------------------------------------
// KS_A: per-block (256-chunk) sums of counts -> partial[NB]
// ---------------------------------------------------------------------------
__global__ __launch_bounds__(256) void ks_a(
    const int* __restrict__ counts, int* __restrict__ partial, int N)
{
    __shared__ int s[256];
    int t = threadIdx.x, i = blockIdx.x * 256 + t;
    s[t] = (i < N) ? counts[i] : 0;
    __syncthreads();
    #pragma unroll
    for (int off = 128; off >= 1; off >>= 1) {
        if (t < off) s[t] += s[t + off];
        __syncthreads();
    }
    if (t == 0) partial[blockIdx.x] = s[0];
}

// ---------------------------------------------------------------------------
// KS_B: single-block exclusive scan of partial[NB], NB <= 1024.
// ---------------------------------------------------------------------------
__global__ __launch_bounds__(1024) void ks_b(int* __restrict__ partial, int NB)
{
    __shared__ int s[1024];
    int t = threadIdx.x;
    s[t] = (t < NB) ? partial[t] : 0;
    __syncthreads();
    #pragma unroll
    for (int off = 1; off < 1024; off <<= 1) {
        int v = (t >= off) ? s[t - off] : 0;
        __syncthreads();
        s[t] += v;
        __syncthreads();
    }
    if (t < NB) partial[t] = (t == 0) ? 0 : s[t - 1];
}

// ---------------------------------------------------------------------------
// KS_C: offsets[i] = partial[block] + exclusive_scan_within_block(counts)
// ---------------------------------------------------------------------------
__global__ __launch_bounds__(256) void ks_c(
    const int* __restrict__ counts, const int* __restrict__ partial,
    int* __restrict__ offsets, int N)
{
    __shared__ int s[256];
    int t = threadIdx.x, i = blockIdx.x * 256 + t;
    int c = (i < N) ? counts[i] : 0;
    s[t] = c;
    __syncthreads();
    #pragma unroll
    for (int off = 1; off < 256; off <<= 1) {
        int v = (t >= off) ? s[t - off] : 0;
        __syncthreads();
        s[t] += v;
        __syncthreads();
    }
    if (i < N) offsets[i] = partial[blockIdx.x] + s[t] - c;  // exclusive
}

// ---------------------------------------------------------------------------
// KSC: scatter srcs into CSR order: sorted_src[offsets[dst] + cursor[dst]++]
// ---------------------------------------------------------------------------
__global__ __launch_bounds__(256) void ksc_scatter(
    const int* __restrict__ ei, int E,
    const int* __restrict__ offsets, int* __restrict__ cursor,
    int* __restrict__ sorted_src)
{
    int t = blockIdx.x * 256 + threadIdx.x;
    if (t >= E) return;
    int src = ei[t];
    int dst = ei[E + t];
    int pos = offsets[dst] + atomIncI(&cursor[dst]);
    sorted_src[pos] = src;
}

// ---------------------------------------------------------------------------
// K1: per wave, 16 nodes x 384 cols via mfma_f32_16x16x32_bf16.
// Writes xl/xr/sk (bf16). sk absorbs both biases (bs + bias_gat).
// A layout: m=lane&15, k=quad*8+j.  C/D: col=lane&15, row=quad*4+reg.
// ---------------------------------------------------------------------------
__global__ __launch_bounds__(256) void k1_gemm(
    const float* __restrict__ x, const float* __restrict__ tf,
    const unsigned short* __restrict__ Wt,
    const float* __restrict__ bias_gat, const float* __restrict__ bs,
    unsigned short* __restrict__ xl_b, unsigned short* __restrict__ xr_b,
    unsigned short* __restrict__ sk_b, int N)
{
    const int lane = threadIdx.x & 63;
    const int wave = blockIdx.x * (blockDim.x >> 6) + (threadIdx.x >> 6);
    const int base = wave * 16;
    if (base >= N) return;
    const int nidx = lane & 15;
    const int quad = lane >> 4;

    int anode = base + nidx; if (anode >= N) anode = N - 1;
    const float* xrow = x  + (size_t)anode * 126;
    const float* trow = tf + (size_t)anode * 2;

    v4f acc[24];
    #pragma unroll
    for (int i = 0; i < 24; ++i) acc[i] = 0.0f;

    #pragma unroll
    for (int ks = 0; ks < 4; ++ks) {
        union { v8bf v; unsigned short u[8]; } aF;
        const int k0 = ks * 32 + quad * 8;
        #pragma unroll
        for (int j = 0; j < 8; ++j) {
            const int k = k0 + j;
            float v = (k < 126) ? xrow[k] : trow[k - 126];
            aF.u[j] = f2b(v);
        }
        const unsigned short* wbase = Wt + (size_t)nidx * 128 + (size_t)k0;
        #pragma unroll
        for (int nt = 0; nt < 24; ++nt) {
            v8bf bF = *reinterpret_cast<const v8bf*>(wbase + nt * (16 * 128));
            acc[nt] = __builtin_amdgcn_mfma_f32_16x16x32_bf16(aF.v, bF, acc[nt], 0, 0, 0);
        }
    }

    float biasv[8];
    #pragma unroll
    for (int h = 0; h < 8; ++h)
        biasv[h] = bs[h * 16 + nidx] + bias_gat[h * 16 + nidx];

    #pragma unroll
    for (int reg = 0; reg < 4; ++reg) {
        const int node = base + quad * 4 + reg;
        if (node < N) {
            const size_t rb = (size_t)node * 128;
            #pragma unroll
            for (int nt = 0; nt < 8; ++nt) {
                const int col = nt * 16 + nidx;
                xl_b[rb + col] = f2b(acc[nt][reg]);
                xr_b[rb + col] = f2b(acc[nt + 8][reg]);
                sk_b[rb + col] = f2b(acc[nt + 16][reg] + biasv[nt]);
            }
        }
    }
}

// ---------------------------------------------------------------------------
// K2: fused segment-reduce + finalize. One wave per dst node.
// Lane covers cols c0=2*lane, c1=2*lane+1 (head h = lane>>3; 8-lane groups).
// Self-loop processed inline (src = node). No atomics, no agg/denom arrays.
// ---------------------------------------------------------------------------
__global__ __launch_bounds__(256) void k2_aggfin(
    const int* __restrict__ offsets, const int* __restrict__ counts,
    const int* __restrict__ sorted_src,
    const unsigned short* __restrict__ xl_b,
    const unsigned short* __restrict__ xr_b,
    const unsigned short* __restrict__ sk_b,
    const float* __restrict__ att,
    const float* __restrict__ Wo, const float* __restrict__ bo,
    float* __restrict__ out, int N)
{
    const int node = (int)((blockIdx.x * (size_t)blockDim.x + threadIdx.x) >> 6);
    const int lane = threadIdx.x & 63;
    if (node >= N) return;

    const float2 a2 = *reinterpret_cast<const float2*>(att + 2 * lane);
    float xr0, xr1;
    b2f2(*reinterpret_cast<const unsigned*>(xr_b + (size_t)node * 128 + 2 * lane), xr0, xr1);

    float acc0 = 0.0f, acc1 = 0.0f, den = 0.0f;

    auto procU = [&](unsigned u) {
        float xl0, xl1;
        b2f2(u, xl0, xl1);
        float m0 = xl0 + xr0, m1 = xl1 + xr1;
        float l0 = m0 > 0.0f ? m0 : NEG_SLOPE * m0;
        float l1 = m1 > 0.0f ? m1 : NEG_SLOPE * m1;
        float t = l0 * a2.x + l1 * a2.y;
        t += __shfl_xor(t, 1, 64);
        t += __shfl_xor(t, 2, 64);
        t += __shfl_xor(t, 4, 64);           // head-group (8 lanes) all-reduce
        float e = expf(t);
        acc0 += e * xl0; acc1 += e * xl1; den += e;
    };
    auto ldxl = [&](int src) {
        return *reinterpret_cast<const unsigned*>(xl_b + (size_t)src * 128 + 2 * lane);
    };

    // self-loop
    procU(ldxl(node));

    const int start = offsets[node];
    const int cnt   = counts[node];
    int i = 0;
    for (; i + 2 <= cnt; i += 2) {
        int s0 = sorted_src[start + i];
        int s1 = sorted_src[start + i + 1];
        unsigned u0 = ldxl(s0);
        unsigned u1 = ldxl(s1);
        procU(u0);
        procU(u1);
    }
    if (i < cnt) procU(ldxl(sorted_src[start + i]));

    // finalize: g = acc/den + sk; elu; dot Wo; sigmoid
    float sk0, sk1;
    b2f2(*reinterpret_cast<const unsigned*>(sk_b + (size_t)node * 128 + 2 * lane), sk0, sk1);
    const float rd = 1.0f / (den + 1e-16f);
    float g0 = acc0 * rd + sk0;
    float g1 = acc1 * rd + sk1;
    float c0 = g0 > 0.0f ? g0 : expf(g0) - 1.0f;
    float c1 = g1 > 0.0f ? g1 : expf(g1) - 1.0f;
    const float2 w2 = *reinterpret_cast<const float2*>(Wo + 2 * lane);
    float s = c0 * w2.x + c1 * w2.y;
    #pragma unroll
    for (int off = 32; off >= 1; off >>= 1) s += __shfl_xor(s, off, 64);
    if (lane == 0) out[node] = 1.0f / (1.0f + expf(-(s + bo[0])));
}

// ---------------------------------------------------------------------------
extern "C" void kernel_launch(void* const* d_in, const int* in_sizes, int n_in,
                              void* d_out, int out_size, void* d_ws, size_t ws_size,
                              hipStream_t stream) {
    const float* x   = (const float*)d_in[0];
    const float* tf  = (const float*)d_in[1];
    const int*   ei  = (const int*)  d_in[2];
    const float* Wl  = (const float*)d_in[3];
    const float* Wr  = (const float*)d_in[4];
    const float* att = (const float*)d_in[5];
    const float* bg  = (const float*)d_in[6];
    const float* Ws  = (const float*)d_in[7];
    const float* bs  = (const float*)d_in[8];
    const float* Wo  = (const float*)d_in[9];
    const float* bo  = (const float*)d_in[10];
    float* out = (float*)d_out;

    const int N = in_sizes[0] / 126;
    const int E = in_sizes[2] / 2;
    const int NB = (N + 255) / 256;   // <= 1024 required (N=100000 -> 391)

    char* ws = (char*)d_ws;
    unsigned short* Wt   = (unsigned short*)ws; ws += (size_t)384 * 128 * 2;
    unsigned short* xl_b = (unsigned short*)ws; ws += (size_t)N * 128 * 2;
    unsigned short* xr_b = (unsigned short*)ws; ws += (size_t)N * 128 * 2;
    unsigned short* sk_b = (unsigned short*)ws; ws += (size_t)N * 128 * 2;
    int* counts  = (int*)ws; ws += (size_t)N * 4;
    int* offsets = (int*)ws; ws += (size_t)N * 4;
    int* cursor  = (int*)ws; ws += (size_t)N * 4;
    int* partial = (int*)ws; ws += (size_t)1024 * 4;
    int* sorted_src = (int*)ws; ws += (size_t)E * 4;
    // total ~82 MB

    hipLaunchKernelGGL(k0_wprep, dim3(192), dim3(256), 0, stream, Wl, Wr, Ws, Wt);
    hipLaunchKernelGGL(kz_zero, dim3((3 * N + 255) / 256), dim3(256), 0, stream,
                       counts, 3 * N);
    hipLaunchKernelGGL(kh_hist, dim3((E + 255) / 256), dim3(256), 0, stream,
                       ei, E, counts);
    hipLaunchKernelGGL(ks_a, dim3(NB), dim3(256), 0, stream, counts, partial, N);
    hipLaunchKernelGGL(ks_b, dim3(1), dim3(1024), 0, stream, partial, NB);
    hipLaunchKernelGGL(ks_c, dim3(NB), dim3(256), 0, stream, counts, partial, offsets, N);
    hipLaunchKernelGGL(ksc_scatter, dim3((E + 255) / 256), dim3(256), 0, stream,
                       ei, E, offsets, cursor, sorted_src);

    const int waves1 = (N + 15) / 16;
    hipLaunchKernelGGL(k1_gemm, dim3((waves1 + 3) / 4), dim3(256), 0, stream,
                       x, tf, Wt, bg, bs, xl_b, xr_b, sk_b, N);

    hipLaunchKernelGGL(k2_aggfin, dim3((N + 3) / 4), dim3(256), 0, stream,
                       offsets, counts, sorted_src, xl_b, xr_b, sk_b,
                       att, Wo, bo, out, N);
}

// Round 3
// 312.829 us; speedup vs baseline: 2.3271x; 1.2618x over previous
//
#include <hip/hip_runtime.h>
#include <hip/hip_bf16.h>

#define NEG_SLOPE 0.2f
#define LOG2E 1.4426950408889634f

typedef __bf16 v8bf __attribute__((ext_vector_type(8)));
typedef float  v4f  __attribute__((ext_vector_type(4)));

static __device__ __forceinline__ unsigned short f2b(float f) {
    unsigned u = __builtin_bit_cast(unsigned, f);
    u += 0x7FFFu + ((u >> 16) & 1u);           // RNE to bf16
    return (unsigned short)(u >> 16);
}
static __device__ __forceinline__ void b2f2(unsigned u, float& lo, float& hi) {
    lo = __builtin_bit_cast(float, u << 16);
    hi = __builtin_bit_cast(float, u & 0xFFFF0000u);
}
static __device__ __forceinline__ void unpack8(uint4 u, float* f) {
    b2f2(u.x, f[0], f[1]); b2f2(u.y, f[2], f[3]);
    b2f2(u.z, f[4], f[5]); b2f2(u.w, f[6], f[7]);
}
static __device__ __forceinline__ int atomIncI(int* p) {
    return __hip_atomic_fetch_add(p, 1, __ATOMIC_RELAXED, __HIP_MEMORY_SCOPE_AGENT);
}

// ---------------------------------------------------------------------------
// kA: fused weight-pack (blocks 0..191) + zero counts (blocks 192..).
// Wt layout: [feat(384)][k(128)] bf16 so MFMA A-frags are contiguous 16B.
// ---------------------------------------------------------------------------
__global__ __launch_bounds__(256) void kA_prep(
    const float* __restrict__ Wl, const float* __restrict__ Wr,
    const float* __restrict__ Ws, unsigned short* __restrict__ Wt,
    int* __restrict__ counts, int N)
{
    int b = blockIdx.x;
    if (b < 192) {
        int t = b * 256 + threadIdx.x;          // < 49152
        int nn = t >> 7, k = t & 127;
        const float* W = (nn < 128) ? Wl : ((nn < 256) ? Wr : Ws);
        Wt[t] = f2b(W[k * 128 + (nn & 127)]);
    } else {
        int t = (b - 192) * 256 + threadIdx.x;
        if (t < N) counts[t] = 0;
    }
}

// ---------------------------------------------------------------------------
// kh_hist: in-degree histogram, 4 edges/thread grid-strided.
// ---------------------------------------------------------------------------
__global__ __launch_bounds__(256) void kh_hist(
    const int* __restrict__ ei, int E, int* __restrict__ counts)
{
    int tid = blockIdx.x * 256 + threadIdx.x;
    int stride = gridDim.x * 256;
    #pragma unroll
    for (int k = 0; k < 4; ++k) {
        int e = tid + k * stride;
        if (e < E) atomIncI(&counts[ei[E + e]]);
    }
}

// ---------------------------------------------------------------------------
// ks_a / ks_b / ks_c: 3-phase exclusive scan of counts -> offsets (+cursor).
// ---------------------------------------------------------------------------
__global__ __launch_bounds__(256) void ks_a(
    const int* __restrict__ counts, int* __restrict__ partial, int N)
{
    __shared__ int s[256];
    int t = threadIdx.x, i = blockIdx.x * 256 + t;
    s[t] = (i < N) ? counts[i] : 0;
    __syncthreads();
    #pragma unroll
    for (int off = 128; off >= 1; off >>= 1) {
        if (t < off) s[t] += s[t + off];
        __syncthreads();
    }
    if (t == 0) partial[blockIdx.x] = s[0];
}

__global__ __launch_bounds__(1024) void ks_b(int* __restrict__ partial, int NB)
{
    __shared__ int s[1024];
    int t = threadIdx.x;
    s[t] = (t < NB) ? partial[t] : 0;
    __syncthreads();
    #pragma unroll
    for (int off = 1; off < 1024; off <<= 1) {
        int v = (t >= off) ? s[t - off] : 0;
        __syncthreads();
        s[t] += v;
        __syncthreads();
    }
    if (t < NB) partial[t] = (t == 0) ? 0 : s[t - 1];
}

__global__ __launch_bounds__(256) void ks_c(
    const int* __restrict__ counts, const int* __restrict__ partial,
    int* __restrict__ offsets, int* __restrict__ cursor, int N)
{
    __shared__ int s[256];
    int t = threadIdx.x, i = blockIdx.x * 256 + t;
    int c = (i < N) ? counts[i] : 0;
    s[t] = c;
    __syncthreads();
    #pragma unroll
    for (int off = 1; off < 256; off <<= 1) {
        int v = (t >= off) ? s[t - off] : 0;
        __syncthreads();
        s[t] += v;
        __syncthreads();
    }
    if (i < N) {
        int o = partial[blockIdx.x] + s[t] - c;  // exclusive
        offsets[i] = o;
        cursor[i] = o;                            // scatter cursor starts at offset
    }
}

// ---------------------------------------------------------------------------
// kF: fused CSR-scatter (blocks < KF_SB) + node GEMM (remaining blocks).
// GEMM: 64 nodes/block, 192 threads = 3 waves; wave w computes output array w
// (0=xl, 1=xr, 2=sk) = 128 feats x 64 nodes. Node rows staged fp32->bf16 in
// LDS ([64][136] halves, +8 pad -> conflict-free b128 B-frags).
// MFMA roles: A = weights (M=feat), B = nodes (N) -> D[feat][node]:
//   col=lane&15 = node, row=quad*4+reg = feat  => lane holds 4 consecutive
//   feats of one node -> packed 8B stores, no transpose needed.
// ---------------------------------------------------------------------------
#define KF_SB  326
#define KF_SPT 16

__global__ __launch_bounds__(192) void kF_scatter_gemm(
    const int* __restrict__ ei, int E,
    int* __restrict__ cursor, int* __restrict__ sorted_src,
    const float* __restrict__ x, const float* __restrict__ tf,
    const unsigned short* __restrict__ Wt,
    const float* __restrict__ bg, const float* __restrict__ bs,
    unsigned short* __restrict__ xl_b, unsigned short* __restrict__ xr_b,
    unsigned short* __restrict__ sk_b, int N)
{
    __shared__ unsigned short lds[64 * 136];
    const int tid = threadIdx.x;

    if (blockIdx.x < KF_SB) {
        const int stride = KF_SB * 192;
        int t0 = blockIdx.x * 192 + tid;
        #pragma unroll
        for (int k = 0; k < KF_SPT; ++k) {
            int e = t0 + k * stride;
            if (e < E) {
                int src = ei[e];
                int dst = ei[E + e];
                int pos = atomIncI(&cursor[dst]);
                sorted_src[pos] = src;
            }
        }
        return;
    }

    const int tb = (int)blockIdx.x - KF_SB;
    const int base = tb * 64;

    // ---- stage 64 node rows (x||tf) into LDS as bf16, rows padded to 136 ----
    #pragma unroll
    for (int t = 0; t < 21; ++t) {
        int idx = tid + t * 192;                 // 0..4031 = 64 rows x 63 float2
        int row = idx / 63;
        int c = idx - row * 63;                  // float2 index within row
        int gr = base + row; if (gr >= N) gr = N - 1;
        float2 v = *reinterpret_cast<const float2*>(x + (size_t)gr * 126 + 2 * c);
        unsigned u = (unsigned)f2b(v.x) | ((unsigned)f2b(v.y) << 16);
        *reinterpret_cast<unsigned*>(&lds[row * 136 + 2 * c]) = u;
    }
    if (tid < 64) {
        int gr = base + tid; if (gr >= N) gr = N - 1;
        float2 v = *reinterpret_cast<const float2*>(tf + (size_t)gr * 2);
        unsigned u = (unsigned)f2b(v.x) | ((unsigned)f2b(v.y) << 16);
        *reinterpret_cast<unsigned*>(&lds[tid * 136 + 126]) = u;
    }
    __syncthreads();

    const int wv = tid >> 6;                     // output array 0..2
    const int lane = tid & 63;
    const int nidx = lane & 15, quad = lane >> 4;

    v4f acc[8][4];                               // [feat-frag][node-frag]
    #pragma unroll
    for (int a = 0; a < 8; ++a)
        #pragma unroll
        for (int b = 0; b < 4; ++b) acc[a][b] = 0.0f;

    #pragma unroll
    for (int ks = 0; ks < 4; ++ks) {
        v8bf bfr[4];
        #pragma unroll
        for (int nf = 0; nf < 4; ++nf)
            bfr[nf] = *reinterpret_cast<const v8bf*>(
                &lds[(nf * 16 + nidx) * 136 + ks * 32 + quad * 8]);
        #pragma unroll
        for (int ft = 0; ft < 8; ++ft) {
            v8bf afr = *reinterpret_cast<const v8bf*>(
                Wt + (size_t)(wv * 128 + ft * 16 + nidx) * 128 + ks * 32 + quad * 8);
            #pragma unroll
            for (int nf = 0; nf < 4; ++nf)
                acc[ft][nf] = __builtin_amdgcn_mfma_f32_16x16x32_bf16(
                    afr, bfr[nf], acc[ft][nf], 0, 0, 0);
        }
    }

    float bias[8][4];
    #pragma unroll
    for (int ft = 0; ft < 8; ++ft)
        #pragma unroll
        for (int r = 0; r < 4; ++r) bias[ft][r] = 0.0f;
    if (wv == 2) {
        #pragma unroll
        for (int ft = 0; ft < 8; ++ft) {
            int f = ft * 16 + quad * 4;
            float4 b1 = *reinterpret_cast<const float4*>(bs + f);
            float4 b2 = *reinterpret_cast<const float4*>(bg + f);
            bias[ft][0] = b1.x + b2.x; bias[ft][1] = b1.y + b2.y;
            bias[ft][2] = b1.z + b2.z; bias[ft][3] = b1.w + b2.w;
        }
    }

    unsigned short* dst = (wv == 0) ? xl_b : ((wv == 1) ? xr_b : sk_b);
    #pragma unroll
    for (int nf = 0; nf < 4; ++nf) {
        int node = base + nf * 16 + nidx;
        if (node < N) {
            #pragma unroll
            for (int ft = 0; ft < 8; ++ft) {
                v4f v = acc[ft][nf];
                uint2 p;
                p.x = (unsigned)f2b(v[0] + bias[ft][0]) |
                      ((unsigned)f2b(v[1] + bias[ft][1]) << 16);
                p.y = (unsigned)f2b(v[2] + bias[ft][2]) |
                      ((unsigned)f2b(v[3] + bias[ft][3]) << 16);
                *reinterpret_cast<uint2*>(dst + (size_t)node * 128 + ft * 16 + quad * 4) = p;
            }
        }
    }
}

// ---------------------------------------------------------------------------
// k2: fused segment-reduce + finalize. One wave per dst node; 4 edge-slots of
// 16 lanes; lane j covers cols 8j..8j+7 via one 16B gather. Head h = j>>1;
// per-head dot closes with ONE pair shuffle. Self-loop = item 0.
// ---------------------------------------------------------------------------
__global__ __launch_bounds__(256) void k2_aggfin(
    const int* __restrict__ offsets, const int* __restrict__ counts,
    const int* __restrict__ sorted_src,
    const unsigned short* __restrict__ xl_b,
    const unsigned short* __restrict__ xr_b,
    const unsigned short* __restrict__ sk_b,
    const float* __restrict__ att,
    const float* __restrict__ Wo, const float* __restrict__ bo,
    float* __restrict__ out, int N)
{
    const int node = (int)((blockIdx.x * (size_t)blockDim.x + threadIdx.x) >> 6);
    const int lane = threadIdx.x & 63;
    if (node >= N) return;
    const int j = lane & 15;                    // col-lane within edge slot
    const int g = lane >> 4;                    // edge slot 0..3
    const int cb = j * 8;                       // first col of this lane

    float4 a0 = *reinterpret_cast<const float4*>(att + cb);
    float4 a1 = *reinterpret_cast<const float4*>(att + cb + 4);
    float av[8] = {a0.x, a0.y, a0.z, a0.w, a1.x, a1.y, a1.z, a1.w};
    float xr[8];
    unpack8(*reinterpret_cast<const uint4*>(xr_b + (size_t)node * 128 + cb), xr);

    float acc[8];
    #pragma unroll
    for (int c = 0; c < 8; ++c) acc[c] = 0.0f;
    float den = 0.0f;

    const int start = offsets[node];
    const int total = counts[node] + 1;         // + self-loop
    const int srcbase = start - 1;

    for (int b0 = 0; b0 < total; b0 += 4) {
        int ii = b0 + g;
        bool valid = ii < total;
        int ic = valid ? ii : 0;
        int src = (ic == 0) ? node : sorted_src[srcbase + ic];
        float xl[8];
        unpack8(*reinterpret_cast<const uint4*>(xl_b + (size_t)src * 128 + cb), xl);
        float t = 0.0f;
        #pragma unroll
        for (int c = 0; c < 8; ++c) {
            float m = xl[c] + xr[c];
            float l = fmaxf(m, NEG_SLOPE * m);  // leaky relu
            t = fmaf(l, av[c], t);
        }
        t += __shfl_xor(t, 1, 64);              // close 16-col head dot
        float e = valid ? exp2f(t * LOG2E) : 0.0f;
        #pragma unroll
        for (int c = 0; c < 8; ++c) acc[c] = fmaf(e, xl[c], acc[c]);
        den += e;
    }

    // merge the 4 edge slots (lanes +-16, +-32 hold same cols)
    #pragma unroll
    for (int c = 0; c < 8; ++c) {
        acc[c] += __shfl_xor(acc[c], 16, 64);
        acc[c] += __shfl_xor(acc[c], 32, 64);
    }
    den += __shfl_xor(den, 16, 64);
    den += __shfl_xor(den, 32, 64);

    float rd = 1.0f / (den + 1e-16f);
    float sk[8];
    unpack8(*reinterpret_cast<const uint4*>(sk_b + (size_t)node * 128 + cb), sk);
    float4 w0 = *reinterpret_cast<const float4*>(Wo + cb);
    float4 w1 = *reinterpret_cast<const float4*>(Wo + cb + 4);
    float wv[8] = {w0.x, w0.y, w0.z, w0.w, w1.x, w1.y, w1.z, w1.w};
    float s = 0.0f;
    #pragma unroll
    for (int c = 0; c < 8; ++c) {
        float gg = fmaf(acc[c], rd, sk[c]);
        float el = gg > 0.0f ? gg : (exp2f(gg * LOG2E) - 1.0f);  // elu
        s = fmaf(el, wv[c], s);
    }
    s += __shfl_xor(s, 1, 64);
    s += __shfl_xor(s, 2, 64);
    s += __shfl_xor(s, 4, 64);
    s += __shfl_xor(s, 8, 64);
    if (lane == 0) {
        float z = s + bo[0];
        out[node] = 1.0f / (1.0f + exp2f(-z * LOG2E));
    }
}

// ---------------------------------------------------------------------------
extern "C" void kernel_launch(void* const* d_in, const int* in_sizes, int n_in,
                              void* d_out, int out_size, void* d_ws, size_t ws_size,
                              hipStream_t stream) {
    const float* x   = (const float*)d_in[0];
    const float* tf  = (const float*)d_in[1];
    const int*   ei  = (const int*)  d_in[2];
    const float* Wl  = (const float*)d_in[3];
    const float* Wr  = (const float*)d_in[4];
    const float* att = (const float*)d_in[5];
    const float* bg  = (const float*)d_in[6];
    const float* Ws  = (const float*)d_in[7];
    const float* bs  = (const float*)d_in[8];
    const float* Wo  = (const float*)d_in[9];
    const float* bo  = (const float*)d_in[10];
    float* out = (float*)d_out;

    const int N = in_sizes[0] / 126;
    const int E = in_sizes[2] / 2;
    const int NB = (N + 255) / 256;     // 391 for N=100000 (must be <= 1024)

    char* ws = (char*)d_ws;
    unsigned short* Wt   = (unsigned short*)ws; ws += (size_t)384 * 128 * 2;
    unsigned short* xl_b = (unsigned short*)ws; ws += (size_t)N * 128 * 2;
    unsigned short* xr_b = (unsigned short*)ws; ws += (size_t)N * 128 * 2;
    unsigned short* sk_b = (unsigned short*)ws; ws += (size_t)N * 128 * 2;
    int* counts  = (int*)ws; ws += (size_t)N * 4;
    int* offsets = (int*)ws; ws += (size_t)N * 4;
    int* cursor  = (int*)ws; ws += (size_t)N * 4;
    int* partial = (int*)ws; ws += (size_t)1024 * 4;
    int* sorted_src = (int*)ws; ws += (size_t)E * 4;

    // 1: weight pack + zero counts
    hipLaunchKernelGGL(kA_prep, dim3(192 + (N + 255) / 256), dim3(256), 0, stream,
                       Wl, Wr, Ws, Wt, counts, N);
    // 2: in-degree histogram
    hipLaunchKernelGGL(kh_hist, dim3((E + 1023) / 1024), dim3(256), 0, stream,
                       ei, E, counts);
    // 3-5: scan -> offsets, cursor
    hipLaunchKernelGGL(ks_a, dim3(NB), dim3(256), 0, stream, counts, partial, N);
    hipLaunchKernelGGL(ks_b, dim3(1), dim3(1024), 0, stream, partial, NB);
    hipLaunchKernelGGL(ks_c, dim3(NB), dim3(256), 0, stream,
                       counts, partial, offsets, cursor, N);
    // 6: fused CSR scatter + node GEMM (overlapped on-device)
    const int GB = (N + 63) / 64;
    hipLaunchKernelGGL(kF_scatter_gemm, dim3(KF_SB + GB), dim3(192), 0, stream,
                       ei, E, cursor, sorted_src, x, tf, Wt, bg, bs,
                       xl_b, xr_b, sk_b, N);
    // 7: segment-reduce + finalize
    hipLaunchKernelGGL(k2_aggfin, dim3((N + 3) / 4), dim3(256), 0, stream,
                       offsets, counts, sorted_src, xl_b, xr_b, sk_b,
                       att, Wo, bo, out, N);
}

// Round 4
// 292.817 us; speedup vs baseline: 2.4862x; 1.0683x over previous
//
#include <hip/hip_runtime.h>
#include <hip/hip_bf16.h>

#define NEG_SLOPE 0.2f
#define LOG2E 1.4426950408889634f

typedef __bf16 v8bf __attribute__((ext_vector_type(8)));
typedef float  v4f  __attribute__((ext_vector_type(4)));

static __device__ __forceinline__ unsigned short f2b(float f) {
    unsigned u = __builtin_bit_cast(unsigned, f);
    u += 0x7FFFu + ((u >> 16) & 1u);           // RNE to bf16
    return (unsigned short)(u >> 16);
}
static __device__ __forceinline__ void b2f2(unsigned u, float& lo, float& hi) {
    lo = __builtin_bit_cast(float, u << 16);
    hi = __builtin_bit_cast(float, u & 0xFFFF0000u);
}
static __device__ __forceinline__ void unpack8(uint4 u, float* f) {
    b2f2(u.x, f[0], f[1]); b2f2(u.y, f[2], f[3]);
    b2f2(u.z, f[4], f[5]); b2f2(u.w, f[6], f[7]);
}
static __device__ __forceinline__ int atomIncI(int* p) {
    return __hip_atomic_fetch_add(p, 1, __ATOMIC_RELAXED, __HIP_MEMORY_SCOPE_AGENT);
}

// ---------------------------------------------------------------------------
// kA: fused weight-pack (blocks 0..191) + zero counts (blocks 192..).
// Wt layout: [feat(384)][k(128)] bf16 so MFMA A-frags are contiguous 16B.
// ---------------------------------------------------------------------------
__global__ __launch_bounds__(256) void kA_prep(
    const float* __restrict__ Wl, const float* __restrict__ Wr,
    const float* __restrict__ Ws, unsigned short* __restrict__ Wt,
    int* __restrict__ counts, int N)
{
    int b = blockIdx.x;
    if (b < 192) {
        int t = b * 256 + threadIdx.x;          // < 49152
        int nn = t >> 7, k = t & 127;
        const float* W = (nn < 128) ? Wl : ((nn < 256) ? Wr : Ws);
        Wt[t] = f2b(W[k * 128 + (nn & 127)]);
    } else {
        int t = (b - 192) * 256 + threadIdx.x;
        if (t < N) counts[t] = 0;
    }
}

// ---------------------------------------------------------------------------
// kB: fused in-degree histogram+rank (blocks < KB_HB) + node GEMM (rest).
// Hist: rank[e] = old value of counts[dst]++  (atomic-with-return); rank is
// this edge's slot within its dst bucket -> scatter later needs NO atomics.
// GEMM: 64 nodes/block, 192 thr = 3 waves; wave w computes array w
// (0=xl,1=xr,2=sk). Node rows staged fp32->bf16 in LDS [64][136] (+8 pad).
// MFMA A=weights, B=nodes -> D: col=node, row=feat -> packed 8B stores.
// ---------------------------------------------------------------------------
#define KB_HB 512

__global__ __launch_bounds__(192) void kB_hist_gemm(
    const int* __restrict__ ei, int E,
    int* __restrict__ counts, int* __restrict__ rank,
    const float* __restrict__ x, const float* __restrict__ tf,
    const unsigned short* __restrict__ Wt,
    const float* __restrict__ bg, const float* __restrict__ bs,
    unsigned short* __restrict__ xl_b, unsigned short* __restrict__ xr_b,
    unsigned short* __restrict__ sk_b, int N)
{
    __shared__ unsigned short lds[64 * 136];
    const int tid = threadIdx.x;

    if (blockIdx.x < KB_HB) {
        const int stride = KB_HB * 192;
        for (int e = blockIdx.x * 192 + tid; e < E; e += stride) {
            int dst = ei[E + e];
            rank[e] = atomIncI(&counts[dst]);
        }
        return;
    }

    const int tb = (int)blockIdx.x - KB_HB;
    const int base = tb * 64;

    // ---- stage 64 node rows (x||tf) into LDS as bf16, rows padded to 136 ----
    #pragma unroll
    for (int t = 0; t < 21; ++t) {
        int idx = tid + t * 192;                 // 0..4031 = 64 rows x 63 float2
        int row = idx / 63;
        int c = idx - row * 63;
        int gr = base + row; if (gr >= N) gr = N - 1;
        float2 v = *reinterpret_cast<const float2*>(x + (size_t)gr * 126 + 2 * c);
        unsigned u = (unsigned)f2b(v.x) | ((unsigned)f2b(v.y) << 16);
        *reinterpret_cast<unsigned*>(&lds[row * 136 + 2 * c]) = u;
    }
    if (tid < 64) {
        int gr = base + tid; if (gr >= N) gr = N - 1;
        float2 v = *reinterpret_cast<const float2*>(tf + (size_t)gr * 2);
        unsigned u = (unsigned)f2b(v.x) | ((unsigned)f2b(v.y) << 16);
        *reinterpret_cast<unsigned*>(&lds[tid * 136 + 126]) = u;
    }
    __syncthreads();

    const int wv = tid >> 6;                     // output array 0..2
    const int lane = tid & 63;
    const int nidx = lane & 15, quad = lane >> 4;

    v4f acc[8][4];                               // [feat-frag][node-frag]
    #pragma unroll
    for (int a = 0; a < 8; ++a)
        #pragma unroll
        for (int b = 0; b < 4; ++b) acc[a][b] = 0.0f;

    #pragma unroll
    for (int ks = 0; ks < 4; ++ks) {
        v8bf bfr[4];
        #pragma unroll
        for (int nf = 0; nf < 4; ++nf)
            bfr[nf] = *reinterpret_cast<const v8bf*>(
                &lds[(nf * 16 + nidx) * 136 + ks * 32 + quad * 8]);
        #pragma unroll
        for (int ft = 0; ft < 8; ++ft) {
            v8bf afr = *reinterpret_cast<const v8bf*>(
                Wt + (size_t)(wv * 128 + ft * 16 + nidx) * 128 + ks * 32 + quad * 8);
            #pragma unroll
            for (int nf = 0; nf < 4; ++nf)
                acc[ft][nf] = __builtin_amdgcn_mfma_f32_16x16x32_bf16(
                    afr, bfr[nf], acc[ft][nf], 0, 0, 0);
        }
    }

    float bias[8][4];
    #pragma unroll
    for (int ft = 0; ft < 8; ++ft)
        #pragma unroll
        for (int r = 0; r < 4; ++r) bias[ft][r] = 0.0f;
    if (wv == 2) {
        #pragma unroll
        for (int ft = 0; ft < 8; ++ft) {
            int f = ft * 16 + quad * 4;
            float4 b1 = *reinterpret_cast<const float4*>(bs + f);
            float4 b2 = *reinterpret_cast<const float4*>(bg + f);
            bias[ft][0] = b1.x + b2.x; bias[ft][1] = b1.y + b2.y;
            bias[ft][2] = b1.z + b2.z; bias[ft][3] = b1.w + b2.w;
        }
    }

    unsigned short* dst = (wv == 0) ? xl_b : ((wv == 1) ? xr_b : sk_b);
    #pragma unroll
    for (int nf = 0; nf < 4; ++nf) {
        int node = base + nf * 16 + nidx;
        if (node < N) {
            #pragma unroll
            for (int ft = 0; ft < 8; ++ft) {
                v4f v = acc[ft][nf];
                uint2 p;
                p.x = (unsigned)f2b(v[0] + bias[ft][0]) |
                      ((unsigned)f2b(v[1] + bias[ft][1]) << 16);
                p.y = (unsigned)f2b(v[2] + bias[ft][2]) |
                      ((unsigned)f2b(v[3] + bias[ft][3]) << 16);
                *reinterpret_cast<uint2*>(dst + (size_t)node * 128 + ft * 16 + quad * 4) = p;
            }
        }
    }
}

// ---------------------------------------------------------------------------
// ks_a: per-256-chunk sums of counts -> partial[NB]
// ---------------------------------------------------------------------------
__global__ __launch_bounds__(256) void ks_a(
    const int* __restrict__ counts, int* __restrict__ partial, int N)
{
    __shared__ int s[256];
    int t = threadIdx.x, i = blockIdx.x * 256 + t;
    s[t] = (i < N) ? counts[i] : 0;
    __syncthreads();
    #pragma unroll
    for (int off = 128; off >= 1; off >>= 1) {
        if (t < off) s[t] += s[t + off];
        __syncthreads();
    }
    if (t == 0) partial[blockIdx.x] = s[0];
}

// ---------------------------------------------------------------------------
// ks_bc: merged global+local scan. Each block (1024 thr) redundantly
// inclusive-scans partial[0..NB) in LDS, then threads 0..255 produce
// range[i] = (start, count) for its 256-node chunk.
// All __syncthreads are executed uniformly (predicated work only).
// ---------------------------------------------------------------------------
__global__ __launch_bounds__(1024) void ks_bc(
    const int* __restrict__ counts, const int* __restrict__ partial,
    int2* __restrict__ range, int N, int NB)
{
    __shared__ int sp[1024];
    __shared__ int sc[256];
    const int t = threadIdx.x;
    sp[t] = (t < NB) ? partial[t] : 0;
    __syncthreads();
    #pragma unroll
    for (int off = 1; off < 1024; off <<= 1) {
        int v = (t >= off) ? sp[t - off] : 0;
        __syncthreads();
        sp[t] += v;
        __syncthreads();
    }
    const int blockbase = (blockIdx.x == 0) ? 0 : sp[blockIdx.x - 1];

    const int i = blockIdx.x * 256 + (t & 255);
    int c = 0;
    if (t < 256) {
        c = (i < N) ? counts[i] : 0;
        sc[t] = c;
    }
    __syncthreads();
    #pragma unroll
    for (int off = 1; off < 256; off <<= 1) {
        int v = 0;
        if (t < 256 && t >= off) v = sc[t - off];
        __syncthreads();
        if (t < 256) sc[t] += v;
        __syncthreads();
    }
    if (t < 256 && i < N)
        range[i] = make_int2(blockbase + sc[t] - c, c);   // exclusive start, count
}

// ---------------------------------------------------------------------------
// kD: atomic-free CSR scatter: sorted_src[range[dst].x + rank[e]] = src.
// Runs right before k2 so the 4 MB dirty sorted_src stays L2-resident.
// ---------------------------------------------------------------------------
__global__ __launch_bounds__(256) void kD_scatter(
    const int* __restrict__ ei, int E,
    const int2* __restrict__ range, const int* __restrict__ rank,
    int* __restrict__ sorted_src)
{
    int tid = blockIdx.x * 256 + threadIdx.x;
    int stride = gridDim.x * 256;
    #pragma unroll
    for (int k = 0; k < 4; ++k) {
        int e = tid + k * stride;
        if (e < E) {
            int src = ei[e];
            int dst = ei[E + e];
            sorted_src[range[dst].x + rank[e]] = src;
        }
    }
}

// ---------------------------------------------------------------------------
// k2: fused segment-reduce + finalize. One wave per dst node; 4 edge-slots of
// 16 lanes; lane j covers cols 8j..8j+7 via one 16B gather. Self-loop = item 0.
// ---------------------------------------------------------------------------
__global__ __launch_bounds__(256) void k2_aggfin(
    const int2* __restrict__ range, const int* __restrict__ sorted_src,
    const unsigned short* __restrict__ xl_b,
    const unsigned short* __restrict__ xr_b,
    const unsigned short* __restrict__ sk_b,
    const float* __restrict__ att,
    const float* __restrict__ Wo, const float* __restrict__ bo,
    float* __restrict__ out, int N)
{
    const int node = (int)((blockIdx.x * (size_t)blockDim.x + threadIdx.x) >> 6);
    const int lane = threadIdx.x & 63;
    if (node >= N) return;
    const int j = lane & 15;                    // col-lane within edge slot
    const int g = lane >> 4;                    // edge slot 0..3
    const int cb = j * 8;                       // first col of this lane

    float4 a0 = *reinterpret_cast<const float4*>(att + cb);
    float4 a1 = *reinterpret_cast<const float4*>(att + cb + 4);
    float av[8] = {a0.x, a0.y, a0.z, a0.w, a1.x, a1.y, a1.z, a1.w};
    float xr[8];
    unpack8(*reinterpret_cast<const uint4*>(xr_b + (size_t)node * 128 + cb), xr);

    float acc[8];
    #pragma unroll
    for (int c = 0; c < 8; ++c) acc[c] = 0.0f;
    float den = 0.0f;

    const int2 rc = range[node];
    const int total = rc.y + 1;                 // + self-loop
    const int srcbase = rc.x - 1;

    for (int b0 = 0; b0 < total; b0 += 4) {
        int ii = b0 + g;
        bool valid = ii < total;
        int ic = valid ? ii : 0;
        int src = (ic == 0) ? node : sorted_src[srcbase + ic];
        float xl[8];
        unpack8(*reinterpret_cast<const uint4*>(xl_b + (size_t)src * 128 + cb), xl);
        float t = 0.0f;
        #pragma unroll
        for (int c = 0; c < 8; ++c) {
            float m = xl[c] + xr[c];
            float l = fmaxf(m, NEG_SLOPE * m);  // leaky relu
            t = fmaf(l, av[c], t);
        }
        t += __shfl_xor(t, 1, 64);              // close 16-col head dot
        float e = valid ? exp2f(t * LOG2E) : 0.0f;
        #pragma unroll
        for (int c = 0; c < 8; ++c) acc[c] = fmaf(e, xl[c], acc[c]);
        den += e;
    }

    // merge the 4 edge slots (lanes +-16, +-32 hold same cols)
    #pragma unroll
    for (int c = 0; c < 8; ++c) {
        acc[c] += __shfl_xor(acc[c], 16, 64);
        acc[c] += __shfl_xor(acc[c], 32, 64);
    }
    den += __shfl_xor(den, 16, 64);
    den += __shfl_xor(den, 32, 64);

    float rd = 1.0f / (den + 1e-16f);
    float sk[8];
    unpack8(*reinterpret_cast<const uint4*>(sk_b + (size_t)node * 128 + cb), sk);
    float4 w0 = *reinterpret_cast<const float4*>(Wo + cb);
    float4 w1 = *reinterpret_cast<const float4*>(Wo + cb + 4);
    float wv[8] = {w0.x, w0.y, w0.z, w0.w, w1.x, w1.y, w1.z, w1.w};
    float s = 0.0f;
    #pragma unroll
    for (int c = 0; c < 8; ++c) {
        float gg = fmaf(acc[c], rd, sk[c]);
        float el = gg > 0.0f ? gg : (exp2f(gg * LOG2E) - 1.0f);  // elu
        s = fmaf(el, wv[c], s);
    }
    s += __shfl_xor(s, 1, 64);
    s += __shfl_xor(s, 2, 64);
    s += __shfl_xor(s, 4, 64);
    s += __shfl_xor(s, 8, 64);
    if (lane == 0) {
        float z = s + bo[0];
        out[node] = 1.0f / (1.0f + exp2f(-z * LOG2E));
    }
}

// ---------------------------------------------------------------------------
extern "C" void kernel_launch(void* const* d_in, const int* in_sizes, int n_in,
                              void* d_out, int out_size, void* d_ws, size_t ws_size,
                              hipStream_t stream) {
    const float* x   = (const float*)d_in[0];
    const float* tf  = (const float*)d_in[1];
    const int*   ei  = (const int*)  d_in[2];
    const float* Wl  = (const float*)d_in[3];
    const float* Wr  = (const float*)d_in[4];
    const float* att = (const float*)d_in[5];
    const float* bg  = (const float*)d_in[6];
    const float* Ws  = (const float*)d_in[7];
    const float* bs  = (const float*)d_in[8];
    const float* Wo  = (const float*)d_in[9];
    const float* bo  = (const float*)d_in[10];
    float* out = (float*)d_out;

    const int N = in_sizes[0] / 126;
    const int E = in_sizes[2] / 2;
    const int NB = (N + 255) / 256;     // 391 for N=100000 (must be <= 1024)

    char* ws = (char*)d_ws;
    unsigned short* Wt   = (unsigned short*)ws; ws += (size_t)384 * 128 * 2;
    unsigned short* xl_b = (unsigned short*)ws; ws += (size_t)N * 128 * 2;
    unsigned short* xr_b = (unsigned short*)ws; ws += (size_t)N * 128 * 2;
    unsigned short* sk_b = (unsigned short*)ws; ws += (size_t)N * 128 * 2;
    int*  counts  = (int*)ws;  ws += (size_t)N * 4;
    int2* range   = (int2*)ws; ws += (size_t)N * 8;
    int*  rank    = (int*)ws;  ws += (size_t)E * 4;
    int*  partial = (int*)ws;  ws += (size_t)1024 * 4;
    int*  sorted_src = (int*)ws; ws += (size_t)E * 4;

    // 1: weight pack + zero counts
    hipLaunchKernelGGL(kA_prep, dim3(192 + (N + 255) / 256), dim3(256), 0, stream,
                       Wl, Wr, Ws, Wt, counts, N);
    // 2: histogram+rank (latency-bound) fused with node GEMM (MFMA-bound)
    const int GB = (N + 63) / 64;
    hipLaunchKernelGGL(kB_hist_gemm, dim3(KB_HB + GB), dim3(192), 0, stream,
                       ei, E, counts, rank, x, tf, Wt, bg, bs,
                       xl_b, xr_b, sk_b, N);
    // 3-4: scan -> range(start,count)
    hipLaunchKernelGGL(ks_a, dim3(NB), dim3(256), 0, stream, counts, partial, N);
    hipLaunchKernelGGL(ks_bc, dim3(NB), dim3(1024), 0, stream,
                       counts, partial, range, N, NB);
    // 5: atomic-free scatter (keeps sorted_src hot in L2 for k2)
    hipLaunchKernelGGL(kD_scatter, dim3((E + 1023) / 1024), dim3(256), 0, stream,
                       ei, E, range, rank, sorted_src);
    // 6: segment-reduce + finalize
    hipLaunchKernelGGL(k2_aggfin, dim3((N + 3) / 4), dim3(256), 0, stream,
                       range, sorted_src, xl_b, xr_b, sk_b,
                       att, Wo, bo, out, N);
}